// Round 4
// baseline (28.876 us; speedup 1.0000x reference)
//
#include <hip/hip_runtime.h>

// YOLO loss forward, MI355X. Memory-bound streaming reduction.
// R4: single fused kernel. 512 persistent blocks (2/CU), CPB=128 double-buffered
//     LDS (61.4 KB), global_load_lds(16B) staging, wave-role split
//     (waves 0-1: box/IoU/noobj on ch0-9; waves 2-3: class on ch10-29),
//     per-block atomicAdd finish. d_out zeroed via hipMemsetAsync.

constexpr int N_IMG  = 2048;
constexpr int NC     = 30;
constexpr int CELLS  = N_IMG * 14 * 14;   // 401408
constexpr int BLOCK  = 256;
constexpr int CPB    = 128;               // cells per chunk
constexpr int NCHUNK = CELLS / CPB;       // 3136
constexpr int GRID   = 512;               // 2 blocks/CU
constexpr float INV14 = 1.0f / 14.0f;
constexpr float INVN  = 1.0f / (float)N_IMG;

__device__ __forceinline__ void gload16(const void* g, void* l) {
    __builtin_amdgcn_global_load_lds(
        (const __attribute__((address_space(1))) void*)g,
        (__attribute__((address_space(3))) void*)l, 16, 0, 0);
}

__global__ __launch_bounds__(BLOCK)
void yolo_fused(const float* __restrict__ pred,
                const float* __restrict__ targ,
                float* __restrict__ out)
{
    __shared__ float sp[2][CPB * NC];   // 2 x 15360 B
    __shared__ float st[2][CPB * NC];   // 2 x 15360 B
    __shared__ float wsum[BLOCK / 64];

    const int tid = threadIdx.x;
    const int bid = blockIdx.x;

    // stage chunk c: 960 float4 per array; linear LDS dest (wave-uniform base
    // + lane*16 -- exactly global_load_lds's required layout).
    auto stage = [&](int buf, int c) {
        const size_t fbase = (size_t)c * (size_t)(CPB * NC);
        const float4* gp = reinterpret_cast<const float4*>(pred + fbase);
        const float4* gt = reinterpret_cast<const float4*>(targ + fbase);
        float4* lp = reinterpret_cast<float4*>(sp[buf]);
        float4* lt = reinterpret_cast<float4*>(st[buf]);
        #pragma unroll
        for (int i = 0; i < 3; ++i)
            gload16(gp + i * BLOCK + tid, lp + i * BLOCK + tid);
        if (tid < 192)                       // waves 0-2 fully active (wave-uniform)
            gload16(gp + 3 * BLOCK + tid, lp + 3 * BLOCK + tid);
        #pragma unroll
        for (int i = 0; i < 3; ++i)
            gload16(gt + i * BLOCK + tid, lt + i * BLOCK + tid);
        if (tid < 192)
            gload16(gt + 3 * BLOCK + tid, lt + 3 * BLOCK + tid);
    };

    float acc = 0.0f;
    stage(0, bid);
    __syncthreads();                         // vmcnt(0) drained by compiler

    int it = 0;
    for (int c = bid; c < NCHUNK; c += GRID, ++it) {
        const int buf = it & 1;
        if (c + GRID < NCHUNK) stage(buf ^ 1, c + GRID);   // issue BEFORE compute

        if (tid < CPB) {
            // ---- role A (waves 0-1): boxes / IoU / conf / noobj, ch 0-9 ----
            const float* cp = &sp[buf][tid * NC];
            const float* ct = &st[buf][tid * NC];
            float pv[10], tv[10];
            const float2* p2 = reinterpret_cast<const float2*>(cp);  // cell*120B: 8B-aligned
            const float2* t2 = reinterpret_cast<const float2*>(ct);
            #pragma unroll
            for (int i = 0; i < 5; ++i) {
                float2 a = p2[i]; pv[2*i] = a.x; pv[2*i+1] = a.y;
                float2 b = t2[i]; tv[2*i] = b.x; tv[2*i+1] = b.y;
            }

            const float coo = (tv[4] > 0.0f) ? 1.0f : 0.0f;

            const float txc = tv[0] * INV14, tyc = tv[1] * INV14;
            const float tx1 = txc - 0.5f * tv[2], ty1 = tyc - 0.5f * tv[3];
            const float tx2 = txc + 0.5f * tv[2], ty2 = tyc + 0.5f * tv[3];
            const float t_area = (tx2 - tx1) * (ty2 - ty1);

            float i0, u0;
            {
                const float xc = pv[0] * INV14, yc = pv[1] * INV14;
                const float x1 = xc - 0.5f * pv[2], y1 = yc - 0.5f * pv[3];
                const float x2 = xc + 0.5f * pv[2], y2 = yc + 0.5f * pv[3];
                const float a1 = (x2 - x1) * (y2 - y1);
                const float wx = fmaxf(fminf(x2, tx2) - fmaxf(x1, tx1), 0.0f);
                const float wy = fmaxf(fminf(y2, ty2) - fmaxf(y1, ty1), 0.0f);
                i0 = wx * wy;
                u0 = a1 + t_area - i0;      // > 0 (w,h >= 0.05)
            }
            float i1, u1;
            {
                const float xc = pv[5] * INV14, yc = pv[6] * INV14;
                const float x1 = xc - 0.5f * pv[7], y1 = yc - 0.5f * pv[8];
                const float x2 = xc + 0.5f * pv[7], y2 = yc + 0.5f * pv[8];
                const float a1 = (x2 - x1) * (y2 - y1);
                const float wx = fmaxf(fminf(x2, tx2) - fmaxf(x1, tx1), 0.0f);
                const float wy = fmaxf(fminf(y2, ty2) - fmaxf(y1, ty1), 0.0f);
                i1 = wx * wy;
                u1 = a1 + t_area - i1;
            }

            // argmax first-max tie-break, divide-free: iou1 > iou0 <=> i1*u0 > i0*u1
            const bool sel = (i1 * u0) > (i0 * u1);
            const float rp0 = sel ? pv[5] : pv[0];
            const float rp1 = sel ? pv[6] : pv[1];
            const float rp2 = sel ? pv[7] : pv[2];
            const float rp3 = sel ? pv[8] : pv[3];
            const float rp4 = sel ? pv[9] : pv[4];
            const float rt0 = sel ? tv[5] : tv[0];
            const float rt1 = sel ? tv[6] : tv[1];
            const float rt2 = sel ? tv[7] : tv[2];
            const float rt3 = sel ? tv[8] : tv[3];
            const float nrp4 = sel ? pv[4] : pv[9];

            const float d0 = rp0 - rt0, d1 = rp1 - rt1;
            const float d2 = sqrtf(rp2) - sqrtf(rt2);
            const float d3 = sqrtf(rp3) - sqrtf(rt3);
            const float loc     = d0*d0 + d1*d1 + d2*d2 + d3*d3;
            const float contain = rp4 * rp4;
            const float notc    = nrp4 * nrp4;
            const float e4 = pv[4] - tv[4], e9 = pv[9] - tv[9];
            const float noobj = e4*e4 + e9*e9;

            acc += coo * (5.0f * loc + 2.0f * contain + notc)
                 + (1.0f - coo) * (0.5f * noobj);
        } else {
            // ---- role B (waves 2-3): class term, ch 10-29 ----
            const int cell = tid - CPB;
            const float* cp = &sp[buf][cell * NC];
            const float* ct = &st[buf][cell * NC];
            const float coo = (ct[4] > 0.0f) ? 1.0f : 0.0f;
            float cls = 0.0f;
            const float2* p2 = reinterpret_cast<const float2*>(cp + 10);  // even offset
            const float2* t2 = reinterpret_cast<const float2*>(ct + 10);
            #pragma unroll
            for (int i = 0; i < 10; ++i) {
                float2 a = p2[i];
                float2 b = t2[i];
                const float dx = a.x - b.x, dy = a.y - b.y;
                cls += dx * dx + dy * dy;
            }
            acc += coo * cls;
        }
        __syncthreads();   // next buffer staged; safe to overwrite read buffer
    }

    // ---- block reduction + one atomic per block ----
    #pragma unroll
    for (int o = 32; o > 0; o >>= 1) acc += __shfl_down(acc, o, 64);
    if ((tid & 63) == 0) wsum[tid >> 6] = acc;
    __syncthreads();
    if (tid == 0)
        atomicAdd(out, (wsum[0] + wsum[1] + wsum[2] + wsum[3]) * INVN);
}

extern "C" void kernel_launch(void* const* d_in, const int* in_sizes, int n_in,
                              void* d_out, int out_size, void* d_ws, size_t ws_size,
                              hipStream_t stream)
{
    const float* pred = (const float*)d_in[0];
    const float* targ = (const float*)d_in[1];
    float* out        = (float*)d_out;

    hipMemsetAsync(out, 0, sizeof(float), stream);   // d_out is poisoned, not re-zeroed
    yolo_fused<<<GRID, BLOCK, 0, stream>>>(pred, targ, out);
}

// Round 5
// 23.655 us; speedup vs baseline: 1.2207x; 1.2207x over previous
//
#include <hip/hip_runtime.h>

// YOLO loss forward, MI355X. Memory-bound streaming reduction.
// R5: R3 structure with full-machine balance: GRID=256 (1 block/CU, ALL CUs),
//     CPB=224, exactly 7 chunks/block. Double-buffered global_load_lds(16B),
//     issue-before-compute, one barrier per chunk. Deterministic 2-dispatch.

constexpr int N_IMG  = 2048;
constexpr int NC     = 30;
constexpr int CELLS  = N_IMG * 14 * 14;   // 401408
constexpr int BLOCK  = 256;
constexpr int CPB    = 224;               // cells per chunk
constexpr int NCHUNK = 7;                 // per block
constexpr int GRID   = 256;               // 256*224*7 = 401408 exact
constexpr float INV14 = 1.0f / 14.0f;

constexpr int NV  = CPB * NC / 4;         // 1680 float4 per array per chunk
constexpr int REM = NV - (NV / BLOCK) * BLOCK;   // 144

__device__ __forceinline__ void gload16(const void* g, void* l) {
    __builtin_amdgcn_global_load_lds(
        (const __attribute__((address_space(1))) void*)g,
        (__attribute__((address_space(3))) void*)l, 16, 0, 0);
}

__device__ __forceinline__ float cell_loss(const float* __restrict__ cp,
                                           const float* __restrict__ ct)
{
    float pv[NC], tv[NC];
    const float2* p2 = reinterpret_cast<const float2*>(cp);  // cell*120B: 8B-aligned
    const float2* t2 = reinterpret_cast<const float2*>(ct);
    #pragma unroll
    for (int i = 0; i < NC / 2; ++i) {
        float2 a = p2[i]; pv[2*i] = a.x; pv[2*i+1] = a.y;
        float2 b = t2[i]; tv[2*i] = b.x; tv[2*i+1] = b.y;
    }

    const float coo = (tv[4] > 0.0f) ? 1.0f : 0.0f;

    const float txc = tv[0] * INV14, tyc = tv[1] * INV14;
    const float tx1 = txc - 0.5f * tv[2], ty1 = tyc - 0.5f * tv[3];
    const float tx2 = txc + 0.5f * tv[2], ty2 = tyc + 0.5f * tv[3];
    const float t_area = (tx2 - tx1) * (ty2 - ty1);

    float i0, u0;
    {
        const float xc = pv[0] * INV14, yc = pv[1] * INV14;
        const float x1 = xc - 0.5f * pv[2], y1 = yc - 0.5f * pv[3];
        const float x2 = xc + 0.5f * pv[2], y2 = yc + 0.5f * pv[3];
        const float a1 = (x2 - x1) * (y2 - y1);
        const float wx = fmaxf(fminf(x2, tx2) - fmaxf(x1, tx1), 0.0f);
        const float wy = fmaxf(fminf(y2, ty2) - fmaxf(y1, ty1), 0.0f);
        i0 = wx * wy;
        u0 = a1 + t_area - i0;            // > 0 (w,h >= 0.05)
    }
    float i1, u1;
    {
        const float xc = pv[5] * INV14, yc = pv[6] * INV14;
        const float x1 = xc - 0.5f * pv[7], y1 = yc - 0.5f * pv[8];
        const float x2 = xc + 0.5f * pv[7], y2 = yc + 0.5f * pv[8];
        const float a1 = (x2 - x1) * (y2 - y1);
        const float wx = fmaxf(fminf(x2, tx2) - fmaxf(x1, tx1), 0.0f);
        const float wy = fmaxf(fminf(y2, ty2) - fmaxf(y1, ty1), 0.0f);
        i1 = wx * wy;
        u1 = a1 + t_area - i1;
    }

    // argmax first-max tie-break, divide-free: iou1 > iou0 <=> i1*u0 > i0*u1
    const bool sel = (i1 * u0) > (i0 * u1);
    const float rp0 = sel ? pv[5] : pv[0];
    const float rp1 = sel ? pv[6] : pv[1];
    const float rp2 = sel ? pv[7] : pv[2];
    const float rp3 = sel ? pv[8] : pv[3];
    const float rp4 = sel ? pv[9] : pv[4];
    const float rt0 = sel ? tv[5] : tv[0];
    const float rt1 = sel ? tv[6] : tv[1];
    const float rt2 = sel ? tv[7] : tv[2];
    const float rt3 = sel ? tv[8] : tv[3];
    const float nrp4 = sel ? pv[4] : pv[9];

    const float d0 = rp0 - rt0, d1 = rp1 - rt1;
    const float d2 = sqrtf(rp2) - sqrtf(rt2);
    const float d3 = sqrtf(rp3) - sqrtf(rt3);
    const float loc     = d0*d0 + d1*d1 + d2*d2 + d3*d3;
    const float contain = rp4 * rp4;
    const float notc    = nrp4 * nrp4;
    const float e4 = pv[4] - tv[4], e9 = pv[9] - tv[9];
    const float noobj = e4*e4 + e9*e9;
    float cls = 0.0f;
    #pragma unroll
    for (int c = 10; c < NC; ++c) { const float d = pv[c] - tv[c]; cls += d*d; }

    return coo * (5.0f * loc + 2.0f * contain + notc + cls)
         + (1.0f - coo) * (0.5f * noobj);
}

__global__ __launch_bounds__(BLOCK)
void yolo_main(const float* __restrict__ pred,
               const float* __restrict__ targ,
               float* __restrict__ partial)
{
    __shared__ float sp[2][CPB * NC];   // 2 x 26880 B
    __shared__ float st[2][CPB * NC];   // 2 x 26880 B  (total 105 KB)

    const int tid = threadIdx.x;
    const int bid = blockIdx.x;

    // stage chunk c into buffer buf. Linear LDS dest; remainder uses tid<144:
    // active lanes start at lane 0 of wave 2, so wave-uniform base + lane*16
    // still lands each 16B slot; wave 3 exec=0 -> no loads issued.
    auto stage = [&](int buf, int c) {
        const size_t fbase = (size_t)(bid * NCHUNK + c) * (size_t)(CPB * NC);
        const float4* gp = reinterpret_cast<const float4*>(pred + fbase);
        const float4* gt = reinterpret_cast<const float4*>(targ + fbase);
        float4* lp = reinterpret_cast<float4*>(sp[buf]);
        float4* lt = reinterpret_cast<float4*>(st[buf]);
        #pragma unroll
        for (int i = 0; i < NV / BLOCK; ++i)            // 6 full rounds
            gload16(gp + i * BLOCK + tid, lp + i * BLOCK + tid);
        if (tid < REM)
            gload16(gp + (NV / BLOCK) * BLOCK + tid, lp + (NV / BLOCK) * BLOCK + tid);
        #pragma unroll
        for (int i = 0; i < NV / BLOCK; ++i)
            gload16(gt + i * BLOCK + tid, lt + i * BLOCK + tid);
        if (tid < REM)
            gload16(gt + (NV / BLOCK) * BLOCK + tid, lt + (NV / BLOCK) * BLOCK + tid);
    };

    stage(0, 0);
    __syncthreads();                    // compiler drains vmcnt(0) at barrier

    float acc = 0.0f;
    #pragma unroll
    for (int c = 0; c < NCHUNK; ++c) {
        const int buf = c & 1;
        if (c + 1 < NCHUNK) stage(buf ^ 1, c + 1);   // issue BEFORE compute
        if (tid < CPB)
            acc += cell_loss(&sp[buf][tid * NC], &st[buf][tid * NC]);
        __syncthreads();                // next buffer complete; cur reusable
    }

    // block reduction
    __shared__ float wsum[BLOCK / 64];
    #pragma unroll
    for (int o = 32; o > 0; o >>= 1) acc += __shfl_down(acc, o, 64);
    if ((tid & 63) == 0) wsum[tid >> 6] = acc;
    __syncthreads();
    if (tid == 0)
        partial[bid] = wsum[0] + wsum[1] + wsum[2] + wsum[3];
}

__global__ __launch_bounds__(64)
void yolo_final(const float* __restrict__ partial, float* __restrict__ out)
{
    const int tid = threadIdx.x;
    double s = 0.0;
    #pragma unroll
    for (int i = 0; i < GRID / 64; ++i) s += (double)partial[tid + i * 64];
    #pragma unroll
    for (int o = 32; o > 0; o >>= 1) s += __shfl_down(s, o, 64);
    if (tid == 0) out[0] = (float)(s / (double)N_IMG);
}

extern "C" void kernel_launch(void* const* d_in, const int* in_sizes, int n_in,
                              void* d_out, int out_size, void* d_ws, size_t ws_size,
                              hipStream_t stream)
{
    const float* pred = (const float*)d_in[0];
    const float* targ = (const float*)d_in[1];
    float* out        = (float*)d_out;
    float* partial    = (float*)d_ws;   // 256 floats = 1 KB

    yolo_main<<<GRID, BLOCK, 0, stream>>>(pred, targ, partial);
    yolo_final<<<1, 64, 0, stream>>>(partial, out);
}

// Round 7
// 23.053 us; speedup vs baseline: 1.2526x; 1.0261x over previous
//
#include <hip/hip_runtime.h>

// YOLO loss forward, MI355X. Memory-bound streaming reduction.
// R7: R6 geometry (GRID=512, 2 blocks/CU, CPB=112, NCHUNK=7) with SAFE staging:
//     pred+targ merged into ONE contiguous LDS buffer per chunk (1680 float4),
//     staged as 6 full 256-lane global_load_lds rounds + tid<144 remainder
//     (2 full waves + one 16-lane group = R5's proven-safe pattern).
//     LESSON (R6): global_load_lds appears to write in 16-lane burst groups;
//     partial groups spill garbage past base+active*16 — keep active lane
//     count ≡ 0 (mod 16) and never let base+lane*16 cross the buffer end.

constexpr int N_IMG  = 2048;
constexpr int NC     = 30;
constexpr int CELLS  = N_IMG * 14 * 14;   // 401408
constexpr int BLOCK  = 256;
constexpr int CPB    = 112;               // cells per chunk
constexpr int NCHUNK = 7;                 // per block
constexpr int GRID   = 512;               // 2 blocks/CU; 512*112*7 = 401408 exact
constexpr float INV14 = 1.0f / 14.0f;

constexpr int FPC   = CPB * NC;           // floats per chunk per array (3360)
constexpr int NVA   = FPC / 4;            // 840 float4 per array
constexpr int NVTOT = 2 * NVA;            // 1680 combined
constexpr int ROUNDS = NVTOT / BLOCK;     // 6
constexpr int REM    = NVTOT - ROUNDS * BLOCK;   // 144 = 2 waves + 16 lanes

__device__ __forceinline__ void gload16(const void* g, void* l) {
    __builtin_amdgcn_global_load_lds(
        (const __attribute__((address_space(1))) void*)g,
        (__attribute__((address_space(3))) void*)l, 16, 0, 0);
}

__device__ __forceinline__ float cell_loss(const float* __restrict__ cp,
                                           const float* __restrict__ ct)
{
    float pv[NC], tv[NC];
    const float2* p2 = reinterpret_cast<const float2*>(cp);  // 8B-aligned
    const float2* t2 = reinterpret_cast<const float2*>(ct);
    #pragma unroll
    for (int i = 0; i < NC / 2; ++i) {
        float2 a = p2[i]; pv[2*i] = a.x; pv[2*i+1] = a.y;
        float2 b = t2[i]; tv[2*i] = b.x; tv[2*i+1] = b.y;
    }

    const float coo = (tv[4] > 0.0f) ? 1.0f : 0.0f;

    const float txc = tv[0] * INV14, tyc = tv[1] * INV14;
    const float tx1 = txc - 0.5f * tv[2], ty1 = tyc - 0.5f * tv[3];
    const float tx2 = txc + 0.5f * tv[2], ty2 = tyc + 0.5f * tv[3];
    const float t_area = (tx2 - tx1) * (ty2 - ty1);

    float i0, u0;
    {
        const float xc = pv[0] * INV14, yc = pv[1] * INV14;
        const float x1 = xc - 0.5f * pv[2], y1 = yc - 0.5f * pv[3];
        const float x2 = xc + 0.5f * pv[2], y2 = yc + 0.5f * pv[3];
        const float a1 = (x2 - x1) * (y2 - y1);
        const float wx = fmaxf(fminf(x2, tx2) - fmaxf(x1, tx1), 0.0f);
        const float wy = fmaxf(fminf(y2, ty2) - fmaxf(y1, ty1), 0.0f);
        i0 = wx * wy;
        u0 = a1 + t_area - i0;            // > 0 (w,h >= 0.05)
    }
    float i1, u1;
    {
        const float xc = pv[5] * INV14, yc = pv[6] * INV14;
        const float x1 = xc - 0.5f * pv[7], y1 = yc - 0.5f * pv[8];
        const float x2 = xc + 0.5f * pv[7], y2 = yc + 0.5f * pv[8];
        const float a1 = (x2 - x1) * (y2 - y1);
        const float wx = fmaxf(fminf(x2, tx2) - fmaxf(x1, tx1), 0.0f);
        const float wy = fmaxf(fminf(y2, ty2) - fmaxf(y1, ty1), 0.0f);
        i1 = wx * wy;
        u1 = a1 + t_area - i1;
    }

    // argmax first-max tie-break, divide-free: iou1 > iou0 <=> i1*u0 > i0*u1
    const bool sel = (i1 * u0) > (i0 * u1);
    const float rp0 = sel ? pv[5] : pv[0];
    const float rp1 = sel ? pv[6] : pv[1];
    const float rp2 = sel ? pv[7] : pv[2];
    const float rp3 = sel ? pv[8] : pv[3];
    const float rp4 = sel ? pv[9] : pv[4];
    const float rt0 = sel ? tv[5] : tv[0];
    const float rt1 = sel ? tv[6] : tv[1];
    const float rt2 = sel ? tv[7] : tv[2];
    const float rt3 = sel ? tv[8] : tv[3];
    const float nrp4 = sel ? pv[4] : pv[9];

    const float d0 = rp0 - rt0, d1 = rp1 - rt1;
    const float d2 = sqrtf(rp2) - sqrtf(rt2);
    const float d3 = sqrtf(rp3) - sqrtf(rt3);
    const float loc     = d0*d0 + d1*d1 + d2*d2 + d3*d3;
    const float contain = rp4 * rp4;
    const float notc    = nrp4 * nrp4;
    const float e4 = pv[4] - tv[4], e9 = pv[9] - tv[9];
    const float noobj = e4*e4 + e9*e9;
    float cls = 0.0f;
    #pragma unroll
    for (int c = 10; c < NC; ++c) { const float d = pv[c] - tv[c]; cls += d*d; }

    return coo * (5.0f * loc + 2.0f * contain + notc + cls)
         + (1.0f - coo) * (0.5f * noobj);
}

__global__ __launch_bounds__(BLOCK)
void yolo_main(const float* __restrict__ pred,
               const float* __restrict__ targ,
               float* __restrict__ partial)
{
    // ONE combined buffer per chunk: floats [0,3360) = pred, [3360,6720) = targ.
    __shared__ float sbuf[2][2 * FPC];    // 2 x 26880 B = 53.76 KB -> 2 blocks/CU

    const int tid = threadIdx.x;
    const int bid = blockIdx.x;

    auto stage = [&](int buf, int c) {
        const size_t fbase = (size_t)(bid * NCHUNK + c) * (size_t)FPC;
        const float4* gp = reinterpret_cast<const float4*>(pred + fbase);
        const float4* gt = reinterpret_cast<const float4*>(targ + fbase);
        float4* lb = reinterpret_cast<float4*>(sbuf[buf]);
        #pragma unroll
        for (int i = 0; i < ROUNDS; ++i) {
            const int idx = i * BLOCK + tid;
            // slot idx: pred for idx<840, targ for idx>=840. Global src is
            // per-lane (sel ok); LDS dest is linear in idx (single buffer).
            const float4* src = (idx < NVA) ? (gp + idx) : (gt + (idx - NVA));
            gload16(src, lb + idx);
        }
        if (tid < REM) {                  // slots 1536..1679, all targ
            const int idx = ROUNDS * BLOCK + tid;
            gload16(gt + (idx - NVA), lb + idx);
        }
    };

    stage(0, 0);
    __syncthreads();                      // compiler drains vmcnt(0) at barrier

    float acc = 0.0f;
    #pragma unroll
    for (int c = 0; c < NCHUNK; ++c) {
        const int buf = c & 1;
        if (c + 1 < NCHUNK) stage(buf ^ 1, c + 1);   // issue BEFORE compute
        if (tid < CPB)
            acc += cell_loss(&sbuf[buf][tid * NC], &sbuf[buf][FPC + tid * NC]);
        __syncthreads();                  // next buffer complete; cur reusable
    }

    // block reduction
    __shared__ float wsum[BLOCK / 64];
    #pragma unroll
    for (int o = 32; o > 0; o >>= 1) acc += __shfl_down(acc, o, 64);
    if ((tid & 63) == 0) wsum[tid >> 6] = acc;
    __syncthreads();
    if (tid == 0)
        partial[bid] = wsum[0] + wsum[1] + wsum[2] + wsum[3];
}

__global__ __launch_bounds__(64)
void yolo_final(const float* __restrict__ partial, float* __restrict__ out)
{
    const int tid = threadIdx.x;
    double s = 0.0;
    #pragma unroll
    for (int i = 0; i < GRID / 64; ++i) s += (double)partial[tid + i * 64];
    #pragma unroll
    for (int o = 32; o > 0; o >>= 1) s += __shfl_down(s, o, 64);
    if (tid == 0) out[0] = (float)(s / (double)N_IMG);
}

extern "C" void kernel_launch(void* const* d_in, const int* in_sizes, int n_in,
                              void* d_out, int out_size, void* d_ws, size_t ws_size,
                              hipStream_t stream)
{
    const float* pred = (const float*)d_in[0];
    const float* targ = (const float*)d_in[1];
    float* out        = (float*)d_out;
    float* partial    = (float*)d_ws;   // 512 floats = 2 KB

    yolo_main<<<GRID, BLOCK, 0, stream>>>(pred, targ, partial);
    yolo_final<<<1, 64, 0, stream>>>(partial, out);
}

// Round 8
// 22.664 us; speedup vs baseline: 1.2741x; 1.0172x over previous
//
#include <hip/hip_runtime.h>

// YOLO loss forward, MI355X. Memory-bound streaming reduction.
// R8: T3/T4 counted-vmcnt 3-deep pipeline (m218 technique, plain HIP):
//     raw s_barrier + manual s_waitcnt vmcnt(4) -- prefetch of chunk k+2 stays
//     in flight ACROSS the barrier; only chunk k+1 is certified complete.
//     CPB=64, 3 buffers x 15.36 KB = 46 KB -> 3 blocks/CU. GRID=768,
//     grid-stride over 6272 chunks.
// LESSONS carried: (R6) global_load_lds writes in 16-lane groups -- active
//     lane count must be ≡0 (mod 16), contiguous from lane 0, and must not
//     cross the dest buffer end. (T4) every wave must issue the SAME number
//     of gloads per stage so vmcnt(N) means the same thing in every wave.

constexpr int N_IMG  = 2048;
constexpr int NC     = 30;
constexpr int CELLS  = N_IMG * 14 * 14;   // 401408
constexpr int BLOCK  = 256;
constexpr int CPB    = 64;                // cells per chunk
constexpr int NCHT   = CELLS / CPB;       // 6272 total chunks
constexpr int GRID   = 768;               // 3 blocks/CU (46 KB LDS each)
constexpr float INV14 = 1.0f / 14.0f;

constexpr int FPB   = 2 * CPB * NC;       // floats per buffer (pred+targ) = 3840
constexpr int SLOTS = FPB / 4;            // 960 float4 slots per buffer
constexpr int SPW   = SLOTS / 4;          // 240 slots per wave
constexpr int PREDS = CPB * NC / 4;       // 480 pred slots

__device__ __forceinline__ void gload16(const void* g, void* l) {
    __builtin_amdgcn_global_load_lds(
        (const __attribute__((address_space(1))) void*)g,
        (__attribute__((address_space(3))) void*)l, 16, 0, 0);
}

__device__ __forceinline__ float cell_loss(const float* __restrict__ cp,
                                           const float* __restrict__ ct)
{
    float pv[NC], tv[NC];
    const float2* p2 = reinterpret_cast<const float2*>(cp);  // 8B-aligned
    const float2* t2 = reinterpret_cast<const float2*>(ct);
    #pragma unroll
    for (int i = 0; i < NC / 2; ++i) {
        float2 a = p2[i]; pv[2*i] = a.x; pv[2*i+1] = a.y;
        float2 b = t2[i]; tv[2*i] = b.x; tv[2*i+1] = b.y;
    }

    const float coo = (tv[4] > 0.0f) ? 1.0f : 0.0f;

    const float txc = tv[0] * INV14, tyc = tv[1] * INV14;
    const float tx1 = txc - 0.5f * tv[2], ty1 = tyc - 0.5f * tv[3];
    const float tx2 = txc + 0.5f * tv[2], ty2 = tyc + 0.5f * tv[3];
    const float t_area = (tx2 - tx1) * (ty2 - ty1);

    float i0, u0;
    {
        const float xc = pv[0] * INV14, yc = pv[1] * INV14;
        const float x1 = xc - 0.5f * pv[2], y1 = yc - 0.5f * pv[3];
        const float x2 = xc + 0.5f * pv[2], y2 = yc + 0.5f * pv[3];
        const float a1 = (x2 - x1) * (y2 - y1);
        const float wx = fmaxf(fminf(x2, tx2) - fmaxf(x1, tx1), 0.0f);
        const float wy = fmaxf(fminf(y2, ty2) - fmaxf(y1, ty1), 0.0f);
        i0 = wx * wy;
        u0 = a1 + t_area - i0;            // > 0 (w,h >= 0.05)
    }
    float i1, u1;
    {
        const float xc = pv[5] * INV14, yc = pv[6] * INV14;
        const float x1 = xc - 0.5f * pv[7], y1 = yc - 0.5f * pv[8];
        const float x2 = xc + 0.5f * pv[7], y2 = yc + 0.5f * pv[8];
        const float a1 = (x2 - x1) * (y2 - y1);
        const float wx = fmaxf(fminf(x2, tx2) - fmaxf(x1, tx1), 0.0f);
        const float wy = fmaxf(fminf(y2, ty2) - fmaxf(y1, ty1), 0.0f);
        i1 = wx * wy;
        u1 = a1 + t_area - i1;
    }

    // argmax first-max tie-break, divide-free: iou1 > iou0 <=> i1*u0 > i0*u1
    const bool sel = (i1 * u0) > (i0 * u1);
    const float rp0 = sel ? pv[5] : pv[0];
    const float rp1 = sel ? pv[6] : pv[1];
    const float rp2 = sel ? pv[7] : pv[2];
    const float rp3 = sel ? pv[8] : pv[3];
    const float rp4 = sel ? pv[9] : pv[4];
    const float rt0 = sel ? tv[5] : tv[0];
    const float rt1 = sel ? tv[6] : tv[1];
    const float rt2 = sel ? tv[7] : tv[2];
    const float rt3 = sel ? tv[8] : tv[3];
    const float nrp4 = sel ? pv[4] : pv[9];

    const float d0 = rp0 - rt0, d1 = rp1 - rt1;
    const float d2 = sqrtf(rp2) - sqrtf(rt2);
    const float d3 = sqrtf(rp3) - sqrtf(rt3);
    const float loc     = d0*d0 + d1*d1 + d2*d2 + d3*d3;
    const float contain = rp4 * rp4;
    const float notc    = nrp4 * nrp4;
    const float e4 = pv[4] - tv[4], e9 = pv[9] - tv[9];
    const float noobj = e4*e4 + e9*e9;
    float cls = 0.0f;
    #pragma unroll
    for (int c = 10; c < NC; ++c) { const float d = pv[c] - tv[c]; cls += d*d; }

    return coo * (5.0f * loc + 2.0f * contain + notc + cls)
         + (1.0f - coo) * (0.5f * noobj);
}

__global__ __launch_bounds__(BLOCK)
void yolo_main(const float* __restrict__ pred,
               const float* __restrict__ targ,
               float* __restrict__ partial)
{
    // buffer layout: floats [0,1920) = pred chunk, [1920,3840) = targ chunk
    __shared__ float sbuf[3 * FPB];       // 3 x 15360 B = 46 KB -> 3 blocks/CU

    const int tid = threadIdx.x;
    const int bid = blockIdx.x;
    const int wv  = tid >> 6;
    const int ln  = tid & 63;

    // stage chunk into lbuf. Per-wave contiguous 240-slot segment:
    // 3 full 64-lane rounds + one 48-lane round (3 x 16-groups from lane 0).
    // EVERY wave issues exactly 4 gloads -> uniform vmcnt accounting.
    auto stage = [&](float* lbuf, int chunk) {
        const size_t fbase = (size_t)chunk * (size_t)(CPB * NC);
        const int wbase = wv * SPW;       // 0,240,480,720
        const float4* gsrc = (wv < 2)
            ? reinterpret_cast<const float4*>(pred + fbase) + wbase
            : reinterpret_cast<const float4*>(targ + fbase) + (wbase - PREDS);
        float4* lb = reinterpret_cast<float4*>(lbuf) + wbase;
        #pragma unroll
        for (int i = 0; i < 3; ++i)
            gload16(gsrc + i * 64 + ln, lb + i * 64 + ln);
        if (ln < 48)
            gload16(gsrc + 192 + ln, lb + 192 + ln);
    };

    const int n = (NCHT - bid + GRID - 1) / GRID;   // 9 (bid<128) or 8

    // prologue: fill buffers 0,1 (8 outstanding); wait oldest 4 -> buf0 ready
    stage(sbuf, bid);
    stage(sbuf + FPB, bid + GRID);
    asm volatile("s_waitcnt vmcnt(4)" ::: "memory");
    __builtin_amdgcn_sched_barrier(0);
    __builtin_amdgcn_s_barrier();
    __builtin_amdgcn_sched_barrier(0);

    float acc = 0.0f;
    for (int k = 0; k < n; ++k) {
        const bool pre = (k + 2 < n);
        if (pre) stage(sbuf + ((k + 2) % 3) * FPB, bid + (k + 2) * GRID);

        if (tid < CPB) {
            const float* b = sbuf + (k % 3) * FPB;
            acc += cell_loss(b + tid * NC, b + CPB * NC + tid * NC);
        }

        // certify buf[k+1] complete; keep buf[k+2]'s 4 loads in flight
        if (pre) asm volatile("s_waitcnt vmcnt(4)" ::: "memory");
        else     asm volatile("s_waitcnt vmcnt(0)" ::: "memory");
        __builtin_amdgcn_sched_barrier(0);
        __builtin_amdgcn_s_barrier();
        __builtin_amdgcn_sched_barrier(0);
    }

    // block reduction
    __shared__ float wsum[BLOCK / 64];
    #pragma unroll
    for (int o = 32; o > 0; o >>= 1) acc += __shfl_down(acc, o, 64);
    if ((tid & 63) == 0) wsum[tid >> 6] = acc;
    __syncthreads();
    if (tid == 0)
        partial[bid] = wsum[0] + wsum[1] + wsum[2] + wsum[3];
}

__global__ __launch_bounds__(64)
void yolo_final(const float* __restrict__ partial, float* __restrict__ out)
{
    const int tid = threadIdx.x;
    double s = 0.0;
    #pragma unroll
    for (int i = 0; i < GRID / 64; ++i) s += (double)partial[tid + i * 64];
    #pragma unroll
    for (int o = 32; o > 0; o >>= 1) s += __shfl_down(s, o, 64);
    if (tid == 0) out[0] = (float)(s / (double)N_IMG);
}

extern "C" void kernel_launch(void* const* d_in, const int* in_sizes, int n_in,
                              void* d_out, int out_size, void* d_ws, size_t ws_size,
                              hipStream_t stream)
{
    const float* pred = (const float*)d_in[0];
    const float* targ = (const float*)d_in[1];
    float* out        = (float*)d_out;
    float* partial    = (float*)d_ws;   // 768 floats = 3 KB

    yolo_main<<<GRID, BLOCK, 0, stream>>>(pred, targ, partial);
    yolo_final<<<1, 64, 0, stream>>>(partial, out);
}